// Round 3
// baseline (781.271 us; speedup 1.0000x reference)
//
#include <hip/hip_runtime.h>

constexpr int TPB = 256;
constexpr int CHUNK = 16384;   // LDS histogram bins per chunk (64 KB -> 2 blocks/CU)

// ------------------------------------------------- LDS-privatized histogram
// grid (P, chunks, 2): arr 0 = row (out-degree), arr 1 = col (in-count).
// Writes NON-ATOMIC per-slice partials [P][N].
__global__ void k_hist(const int* __restrict__ ei, int E, int N, int sliceLen,
                       int* __restrict__ partialR, int* __restrict__ partialC) {
    __shared__ int lh[CHUNK];
    const int p = blockIdx.x, chunk = blockIdx.y, arr = blockIdx.z;
    const int lo = chunk * CHUNK;
    const int hi = min(lo + CHUNK, N);
    for (int t = threadIdx.x; t < CHUNK; t += TPB) lh[t] = 0;
    __syncthreads();
    const int* idx = ei + (size_t)arr * E;
    const int s = p * sliceLen, send = min(s + sliceLen, E);
    for (int e = s + threadIdx.x; e < send; e += TPB) {
        int v = idx[e];
        if (v >= lo && v < hi) atomicAdd(&lh[v - lo], 1);
    }
    __syncthreads();
    int* outp = (arr == 0 ? partialR : partialC) + (size_t)p * N;
    for (int t = lo + threadIdx.x; t < hi; t += TPB) outp[t] = lh[t - lo];
}

// ------------------------------------------------- reduce partials per bin
// dis = rsqrt(sum_p partialR); partialC -> in-place exclusive prefix over p;
// cnt = total in-count.
__global__ void k_reduce(const int* __restrict__ partialR, int* __restrict__ partialC,
                         int N, int P, float* __restrict__ dis, int* __restrict__ cnt) {
    int i = blockIdx.x * blockDim.x + threadIdx.x;
    if (i >= N) return;
    int dg = 0;
    for (int p = 0; p < P; p++) dg += partialR[(size_t)p * N + i];
    dis[i] = (dg > 0) ? rsqrtf((float)dg) : 0.0f;
    int run = 0;
    for (int p = 0; p < P; p++) {
        size_t o = (size_t)p * N + i;
        int v = partialC[o];
        partialC[o] = run;
        run += v;
    }
    cnt[i] = run;
}

// ---------------------------------------------------------------- scan (3-phase)
__global__ void k_scan1(const int* __restrict__ cnt, int* __restrict__ bsum, int N) {
    __shared__ int s[256];
    int i = blockIdx.x * 256 + threadIdx.x;
    s[threadIdx.x] = (i < N) ? cnt[i] : 0;
    __syncthreads();
    for (int off = 128; off > 0; off >>= 1) {
        if (threadIdx.x < off) s[threadIdx.x] += s[threadIdx.x + off];
        __syncthreads();
    }
    if (threadIdx.x == 0) bsum[blockIdx.x] = s[0];
}

__global__ void k_scan2(int* __restrict__ bsum, int NB) {
    __shared__ int tmp[2][256];
    __shared__ int carry_s;
    int t = threadIdx.x;
    if (t == 0) carry_s = 0;
    __syncthreads();
    for (int chunk = 0; chunk < NB; chunk += 256) {
        int idx = chunk + t;
        int v = (idx < NB) ? bsum[idx] : 0;
        int buf = 0;
        tmp[0][t] = v;
        __syncthreads();
        for (int off = 1; off < 256; off <<= 1) {
            int nv = tmp[buf][t] + ((t >= off) ? tmp[buf][t - off] : 0);
            buf ^= 1;
            tmp[buf][t] = nv;
            __syncthreads();
        }
        int incl = tmp[buf][t];
        int carry = carry_s;
        if (idx < NB) bsum[idx] = carry + incl - v;
        __syncthreads();
        if (t == 255) carry_s = carry + incl;
        __syncthreads();
    }
}

// base[i] = global exclusive prefix of cnt; then offC[p][i] += base[i]
__global__ void k_scan3(const int* __restrict__ cnt, const int* __restrict__ bsum,
                        int* __restrict__ base, int* __restrict__ offC, int N, int P) {
    __shared__ int tmp[2][256];
    int t = threadIdx.x;
    int i = blockIdx.x * 256 + t;
    int v = (i < N) ? cnt[i] : 0;
    int buf = 0;
    tmp[0][t] = v;
    __syncthreads();
    for (int off = 1; off < 256; off <<= 1) {
        int nv = tmp[buf][t] + ((t >= off) ? tmp[buf][t - off] : 0);
        buf ^= 1;
        tmp[buf][t] = nv;
        __syncthreads();
    }
    int incl = tmp[buf][t];
    if (i < N) {
        int b = bsum[blockIdx.x] + incl - v;
        base[i] = b;
        for (int p = 0; p < P; p++) offC[(size_t)p * N + i] += b;
    }
}

// ------------------------------------------- CSR scatter, NO global atomics
// pos = offC[p][c] + LDS-local rank; rec[pos] = {row, nrm, nrm*ea.x, nrm*ea.y}
__global__ void k_scatter2(const int* __restrict__ ei, const float* __restrict__ ea,
                           const float* __restrict__ dis, const int* __restrict__ offC,
                           int4* __restrict__ rec, int E, int N, int sliceLen) {
    __shared__ int lc[CHUNK];
    const int p = blockIdx.x, chunk = blockIdx.y;
    const int lo = chunk * CHUNK;
    const int hi = min(lo + CHUNK, N);
    for (int t = threadIdx.x; t < CHUNK; t += TPB) lc[t] = 0;
    __syncthreads();
    const int* colA = ei + E;
    const int* offp = offC + (size_t)p * N;
    const int s = p * sliceLen, send = min(s + sliceLen, E);
    for (int e = s + threadIdx.x; e < send; e += TPB) {
        int c = colA[e];
        if (c < lo || c >= hi) continue;
        int r = ei[e];
        float nrm = dis[r] * dis[c];
        float2 ev = ((const float2*)ea)[e];
        int pos = offp[c] + atomicAdd(&lc[c - lo], 1);
        int4 rv;
        rv.x = r;
        rv.y = __float_as_int(nrm);
        rv.z = __float_as_int(nrm * ev.x);
        rv.w = __float_as_int(nrm * ev.y);
        rec[pos] = rv;
    }
}

// ------------------------------------------- gather L1 + node update (fused)
__global__ void k_gather1(const float* __restrict__ x, const int4* __restrict__ rec,
                          const int* __restrict__ base, const int* __restrict__ cnt,
                          const float* __restrict__ Wc, const float* __restrict__ bc,
                          const float* __restrict__ Wn,
                          float* __restrict__ h, int N) {
    __shared__ float sWc[3 * 16], sbc[16], sWn[5 * 16];
    for (int t = threadIdx.x; t < 48; t += blockDim.x) sWc[t] = Wc[t];
    for (int t = threadIdx.x; t < 16; t += blockDim.x) sbc[t] = bc[t];
    for (int t = threadIdx.x; t < 80; t += blockDim.x) sWn[t] = Wn[t];
    __syncthreads();
    int i = blockIdx.x * blockDim.x + threadIdx.x;
    if (i >= N) return;
    int b0 = base[i], dg = cnt[i];
    float a0 = 0, a1 = 0, a2 = 0, a3 = 0, a4 = 0;
    for (int k = 0; k < dg; k++) {
        int4 rv = rec[b0 + k];
        float nrm = __int_as_float(rv.y);
        const float* xr = x + 3 * (long)rv.x;
        a0 += nrm * xr[0];
        a1 += nrm * xr[1];
        a2 += nrm * xr[2];
        a3 += __int_as_float(rv.z);
        a4 += __int_as_float(rv.w);
    }
    float inv = 1.0f / fmaxf((float)dg, 1.0f);
    float m[5] = {a0 * inv, a1 * inv, a2 * inv, a3 * inv, a4 * inv};
    float xv[3];
#pragma unroll
    for (int j = 0; j < 3; j++) xv[j] = x[3 * (long)i + j];
    float o[16];
#pragma unroll
    for (int k = 0; k < 16; k++) {
        float v = sbc[k];
#pragma unroll
        for (int j = 0; j < 3; j++) v += xv[j] * sWc[j * 16 + k];
#pragma unroll
        for (int j = 0; j < 5; j++) v += m[j] * sWn[j * 16 + k];
        o[k] = fmaxf(v, 0.0f);
    }
    float4* hp = (float4*)(h + 16 * (long)i);
#pragma unroll
    for (int q = 0; q < 4; q++)
        hp[q] = make_float4(o[4 * q], o[4 * q + 1], o[4 * q + 2], o[4 * q + 3]);
}

// ------------------------------- gather L2 + node update + pooling (fused)
__global__ void k_gather2(const float* __restrict__ h, const int4* __restrict__ rec,
                          const int* __restrict__ base, const int* __restrict__ cnt,
                          const int* __restrict__ batch,
                          const float* __restrict__ Wc, const float* __restrict__ bc,
                          const float* __restrict__ Wn,
                          float* __restrict__ pool, int* __restrict__ poolcnt, int N) {
    __shared__ float sWc[16 * 16], sbc[16], sWn[18 * 16];
    __shared__ float sp[64 * 16];
    __shared__ int   sc[64];
    for (int t = threadIdx.x; t < 256; t += blockDim.x) sWc[t] = Wc[t];
    for (int t = threadIdx.x; t < 16;  t += blockDim.x) sbc[t] = bc[t];
    for (int t = threadIdx.x; t < 288; t += blockDim.x) sWn[t] = Wn[t];
    for (int t = threadIdx.x; t < 1024; t += blockDim.x) sp[t] = 0.0f;
    for (int t = threadIdx.x; t < 64;  t += blockDim.x) sc[t] = 0;
    __syncthreads();
    int i = blockIdx.x * blockDim.x + threadIdx.x;
    if (i < N) {
        int b0 = base[i], dg = cnt[i];
        float m[18];
#pragma unroll
        for (int j = 0; j < 18; j++) m[j] = 0.0f;
        for (int k = 0; k < dg; k++) {
            int4 rv = rec[b0 + k];
            float nrm = __int_as_float(rv.y);
            const float4* hr = (const float4*)(h + 16 * (long)rv.x);
            float4 h0 = hr[0], h1 = hr[1], h2 = hr[2], h3 = hr[3];
            m[0]  += nrm * h0.x;  m[1]  += nrm * h0.y;
            m[2]  += nrm * h0.z;  m[3]  += nrm * h0.w;
            m[4]  += nrm * h1.x;  m[5]  += nrm * h1.y;
            m[6]  += nrm * h1.z;  m[7]  += nrm * h1.w;
            m[8]  += nrm * h2.x;  m[9]  += nrm * h2.y;
            m[10] += nrm * h2.z;  m[11] += nrm * h2.w;
            m[12] += nrm * h3.x;  m[13] += nrm * h3.y;
            m[14] += nrm * h3.z;  m[15] += nrm * h3.w;
            m[16] += __int_as_float(rv.z);
            m[17] += __int_as_float(rv.w);
        }
        float inv = 1.0f / fmaxf((float)dg, 1.0f);
#pragma unroll
        for (int j = 0; j < 18; j++) m[j] *= inv;
        float hv[16];
        const float4* hp = (const float4*)(h + 16 * (long)i);
#pragma unroll
        for (int q = 0; q < 4; q++) {
            float4 t4 = hp[q];
            hv[4 * q] = t4.x; hv[4 * q + 1] = t4.y;
            hv[4 * q + 2] = t4.z; hv[4 * q + 3] = t4.w;
        }
        int b = batch[i];
        atomicAdd(&sc[b], 1);
#pragma unroll
        for (int k = 0; k < 16; k++) {
            float v = sbc[k];
#pragma unroll
            for (int j = 0; j < 16; j++) v += hv[j] * sWc[j * 16 + k];
#pragma unroll
            for (int j = 0; j < 18; j++) v += m[j] * sWn[j * 16 + k];
            v = fmaxf(v, 0.0f);
            unsafeAtomicAdd(&sp[b * 16 + k], v);
        }
    }
    __syncthreads();
    for (int t = threadIdx.x; t < 1024; t += blockDim.x)
        if (sp[t] != 0.0f) unsafeAtomicAdd(&pool[t], sp[t]);
    for (int t = threadIdx.x; t < 64; t += blockDim.x)
        if (sc[t]) atomicAdd(&poolcnt[t], sc[t]);
}

// ---------------------------------------------------------------- MLP head
__global__ void k_final(const float* __restrict__ pool, const int* __restrict__ poolcnt,
                        const float* __restrict__ Wl1, const float* __restrict__ bl1,
                        const float* __restrict__ Wl2, const float* __restrict__ bl2,
                        float* __restrict__ out) {
    int g = threadIdx.x;
    if (g >= 64) return;
    float inv = 1.0f / fmaxf((float)poolcnt[g], 1.0f);
    float gv[16];
#pragma unroll
    for (int k = 0; k < 16; k++) gv[k] = pool[g * 16 + k] * inv;
    float t[16];
#pragma unroll
    for (int k = 0; k < 16; k++) {
        float v = bl1[k];
#pragma unroll
        for (int j = 0; j < 16; j++) v += gv[j] * Wl1[j * 16 + k];
        t[k] = fmaxf(v, 0.0f);
    }
    float o0 = bl2[0], o1 = bl2[1];
#pragma unroll
    for (int j = 0; j < 16; j++) {
        o0 += t[j] * Wl2[j * 2 + 0];
        o1 += t[j] * Wl2[j * 2 + 1];
    }
    out[2 * g + 0] = o0;
    out[2 * g + 1] = o1;
}

extern "C" void kernel_launch(void* const* d_in, const int* in_sizes, int n_in,
                              void* d_out, int out_size, void* d_ws, size_t ws_size,
                              hipStream_t stream) {
    const float* x     = (const float*)d_in[0];
    const int*   ei    = (const int*)  d_in[1];
    const float* ea    = (const float*)d_in[2];
    const int*   batch = (const int*)  d_in[3];
    const float* Wc1   = (const float*)d_in[4];
    const float* bc1   = (const float*)d_in[5];
    const float* Wn1   = (const float*)d_in[6];
    const float* Wc2   = (const float*)d_in[7];
    const float* bc2   = (const float*)d_in[8];
    const float* Wn2   = (const float*)d_in[9];
    const float* Wl1   = (const float*)d_in[10];
    const float* bl1   = (const float*)d_in[11];
    const float* Wl2   = (const float*)d_in[12];
    const float* bl2   = (const float*)d_in[13];
    float* out = (float*)d_out;

    const int N = in_sizes[0] / 3;
    const int E = in_sizes[1] / 2;
    const int NB = (N + 255) / 256;
    const int chunks = (N + CHUNK - 1) / CHUNK;

    // adaptive slice count P: shrink if workspace is tight
    auto wsNeeded = [&](int P) -> size_t {
        size_t s = 0;
        s += ((size_t)64 * 16 * 4 + 64 * 4 + 511) & ~(size_t)255;   // pool+poolcnt
        s += 4 * (((size_t)N * 4 + 255) & ~(size_t)255);            // dis,cnt,base + slack
        s += ((size_t)NB * 4 + 255) & ~(size_t)255;                 // bsum
        s += (size_t)P * N * 4;                                     // partialC (offTab)
        size_t trans = (size_t)P * N * 4;                           // partialR
        size_t recb  = (size_t)E * 16;                              // rec
        s += (trans > recb ? trans : recb);
        s += (size_t)N * 16 * 4;                                    // h
        return s + 4096;
    };
    int P = 32;
    while (P > 4 && wsNeeded(P) > ws_size) P >>= 1;
    const int sliceLen = (E + P - 1) / P;

    char* ws = (char*)d_ws;
    size_t o = 0;
    auto alloc = [&](size_t bytes) {
        void* p = ws + o;
        o += (bytes + 255) & ~(size_t)255;
        return p;
    };
    // zeroed region first (pool + poolcnt only)
    float* pool    = (float*)alloc(64 * 16 * 4);
    int*   poolcnt = (int*)  alloc(64 * 4);
    size_t zbytes = o;
    // non-zeroed (all fully overwritten before read)
    float* dis  = (float*)alloc((size_t)N * 4);
    int*   cnt  = (int*)  alloc((size_t)N * 4);
    int*   base = (int*)  alloc((size_t)N * 4);
    int*   bsum = (int*)  alloc((size_t)NB * 4);
    int*   partialC = (int*)alloc((size_t)P * N * 4);     // becomes offTab
    // overlay: partialR (dead after k_reduce) shares space with rec
    size_t ovStart = o;
    int*   partialR = (int*)(ws + ovStart);
    size_t trans = (size_t)P * N * 4, recb = (size_t)E * 16;
    int4*  rec = (int4*)(ws + ovStart);
    o = ovStart + ((trans > recb ? trans : recb) + 255) & ~(size_t)255;
    float* h = (float*)alloc((size_t)N * 16 * 4);
    (void)ws_size;

    hipMemsetAsync(d_ws, 0, zbytes, stream);

    int gN = (N + TPB - 1) / TPB;
    k_hist    <<<dim3(P, chunks, 2), TPB, 0, stream>>>(ei, E, N, sliceLen,
                                                       partialR, partialC);
    k_reduce  <<<gN, TPB, 0, stream>>>(partialR, partialC, N, P, dis, cnt);
    k_scan1   <<<NB, 256, 0, stream>>>(cnt, bsum, N);
    k_scan2   <<<1, 256, 0, stream>>>(bsum, NB);
    k_scan3   <<<NB, 256, 0, stream>>>(cnt, bsum, base, partialC, N, P);
    k_scatter2<<<dim3(P, chunks), TPB, 0, stream>>>(ei, ea, dis, partialC, rec,
                                                    E, N, sliceLen);
    k_gather1 <<<gN, TPB, 0, stream>>>(x, rec, base, cnt, Wc1, bc1, Wn1, h, N);
    k_gather2 <<<gN, TPB, 0, stream>>>(h, rec, base, cnt, batch, Wc2, bc2, Wn2,
                                       pool, poolcnt, N);
    k_final   <<<1, 64, 0, stream>>>(pool, poolcnt, Wl1, bl1, Wl2, bl2, out);
}

// Round 4
// 538.655 us; speedup vs baseline: 1.4504x; 1.4504x over previous
//
#include <hip/hip_runtime.h>

constexpr int TPB = 256;
constexpr int CBITS = 15;              // 32768 u16 bins per chunk, packed in 64 KB LDS
constexpr int CBINS = 1 << CBITS;

// ------------------------------------------------- LDS-privatized histogram
// grid (P, chunks, 2): arr 0 = row (out-degree), arr 1 = col (in-count).
// u16-packed bins; writes NON-ATOMIC per-slice u16 partials [P][NN].
__global__ void k_hist(const int* __restrict__ ei, int E, int N, int sliceLen,
                       unsigned short* __restrict__ partialR,
                       unsigned short* __restrict__ partialC, int NN) {
    __shared__ unsigned int lh[CBINS / 2];
    const int p = blockIdx.x, chunk = blockIdx.y, arr = blockIdx.z;
    const int lo = chunk << CBITS;
    const int hi = min(lo + CBINS, N);
    for (int t = threadIdx.x; t < CBINS / 2; t += TPB) lh[t] = 0;
    __syncthreads();
    const int* idx = ei + (size_t)arr * E;
    const int s = p * sliceLen, send = min(s + sliceLen, E);
    for (int e = s + threadIdx.x; e < send; e += TPB) {
        int v = idx[e];
        if (v >= lo && v < hi) {
            int b = v - lo;
            atomicAdd(&lh[b >> 1], (b & 1) ? 0x10000u : 1u);
        }
    }
    __syncthreads();
    unsigned int* outp = (unsigned int*)((arr == 0 ? partialR : partialC)
                                         + (size_t)p * NN) + (lo >> 1);
    const int nInts = (hi - lo + 1) >> 1;
    for (int t = threadIdx.x; t < nInts; t += TPB) outp[t] = lh[t];
}

// --------------------------------- reduce partials + fused scan1 block sums
// dis = rsqrt(sum_p partialR); partialC -> in-place exclusive prefix over p
// (stays u16: bounded by degree); cnt = total; bsum[block] = sum of cnt.
__global__ void k_reduce(const unsigned short* __restrict__ partialR,
                         unsigned short* __restrict__ partialC,
                         int N, int NN, int P,
                         float* __restrict__ dis, int* __restrict__ cnt,
                         int* __restrict__ bsum) {
    __shared__ int s[256];
    int i = blockIdx.x * 256 + threadIdx.x;
    int run = 0;
    if (i < N) {
        int dg = 0;
        for (int p = 0; p < P; p++) dg += partialR[(size_t)p * NN + i];
        dis[i] = (dg > 0) ? rsqrtf((float)dg) : 0.0f;
        for (int p = 0; p < P; p++) {
            size_t o = (size_t)p * NN + i;
            int v = partialC[o];
            partialC[o] = (unsigned short)run;
            run += v;
        }
        cnt[i] = run;
    }
    s[threadIdx.x] = run;
    __syncthreads();
    for (int off = 128; off > 0; off >>= 1) {
        if (threadIdx.x < off) s[threadIdx.x] += s[threadIdx.x + off];
        __syncthreads();
    }
    if (threadIdx.x == 0) bsum[blockIdx.x] = s[0];
}

// in-place exclusive scan of bsum[0..NB), single block, chunked
__global__ void k_scan2(int* __restrict__ bsum, int NB) {
    __shared__ int tmp[2][256];
    __shared__ int carry_s;
    int t = threadIdx.x;
    if (t == 0) carry_s = 0;
    __syncthreads();
    for (int chunk = 0; chunk < NB; chunk += 256) {
        int idx = chunk + t;
        int v = (idx < NB) ? bsum[idx] : 0;
        int buf = 0;
        tmp[0][t] = v;
        __syncthreads();
        for (int off = 1; off < 256; off <<= 1) {
            int nv = tmp[buf][t] + ((t >= off) ? tmp[buf][t - off] : 0);
            buf ^= 1;
            tmp[buf][t] = nv;
            __syncthreads();
        }
        int incl = tmp[buf][t];
        int carry = carry_s;
        if (idx < NB) bsum[idx] = carry + incl - v;
        __syncthreads();
        if (t == 255) carry_s = carry + incl;
        __syncthreads();
    }
}

// base[i] = global exclusive prefix of cnt
__global__ void k_scan3(const int* __restrict__ cnt, const int* __restrict__ bsum,
                        int* __restrict__ base, int N) {
    __shared__ int tmp[2][256];
    int t = threadIdx.x;
    int i = blockIdx.x * 256 + t;
    int v = (i < N) ? cnt[i] : 0;
    int buf = 0;
    tmp[0][t] = v;
    __syncthreads();
    for (int off = 1; off < 256; off <<= 1) {
        int nv = tmp[buf][t] + ((t >= off) ? tmp[buf][t - off] : 0);
        buf ^= 1;
        tmp[buf][t] = nv;
        __syncthreads();
    }
    int incl = tmp[buf][t];
    if (i < N) base[i] = bsum[blockIdx.x] + incl - v;
}

// ------------------------------------------- CSR scatter, NO global atomics
// pos = base[c] + offC[p][c] + LDS-local rank (u16-packed counters)
__global__ void k_scatter(const int* __restrict__ ei, const float* __restrict__ ea,
                          const float* __restrict__ dis,
                          const int* __restrict__ base,
                          const unsigned short* __restrict__ offC,
                          int4* __restrict__ rec, int E, int N, int NN, int sliceLen) {
    __shared__ unsigned int lc[CBINS / 2];
    const int p = blockIdx.x, chunk = blockIdx.y;
    const int lo = chunk << CBITS;
    const int hi = min(lo + CBINS, N);
    for (int t = threadIdx.x; t < CBINS / 2; t += TPB) lc[t] = 0;
    __syncthreads();
    const int* colA = ei + E;
    const unsigned short* offp = offC + (size_t)p * NN;
    const int s = p * sliceLen, send = min(s + sliceLen, E);
    for (int e = s + threadIdx.x; e < send; e += TPB) {
        int c = colA[e];
        if (c < lo || c >= hi) continue;
        int b = c - lo;
        unsigned int old = atomicAdd(&lc[b >> 1], (b & 1) ? 0x10000u : 1u);
        int rank = (b & 1) ? (int)(old >> 16) : (int)(old & 0xffffu);
        int r = ei[e];
        float nrm = dis[r] * dis[c];
        float2 ev = ((const float2*)ea)[e];
        int pos = base[c] + (int)offp[c] + rank;
        int4 rv;
        rv.x = r;
        rv.y = __float_as_int(nrm);
        rv.z = __float_as_int(nrm * ev.x);
        rv.w = __float_as_int(nrm * ev.y);
        rec[pos] = rv;
    }
}

// ------------------------------------------- gather L1 + node update (fused)
__global__ void k_gather1(const float* __restrict__ x, const int4* __restrict__ rec,
                          const int* __restrict__ base, const int* __restrict__ cnt,
                          const float* __restrict__ Wc, const float* __restrict__ bc,
                          const float* __restrict__ Wn,
                          float* __restrict__ h, int N) {
    __shared__ float sWc[3 * 16], sbc[16], sWn[5 * 16];
    for (int t = threadIdx.x; t < 48; t += blockDim.x) sWc[t] = Wc[t];
    for (int t = threadIdx.x; t < 16; t += blockDim.x) sbc[t] = bc[t];
    for (int t = threadIdx.x; t < 80; t += blockDim.x) sWn[t] = Wn[t];
    __syncthreads();
    int i = blockIdx.x * blockDim.x + threadIdx.x;
    if (i >= N) return;
    int b0 = base[i], dg = cnt[i];
    float a0 = 0, a1 = 0, a2 = 0, a3 = 0, a4 = 0;
    for (int k = 0; k < dg; k++) {
        int4 rv = rec[b0 + k];
        float nrm = __int_as_float(rv.y);
        const float* xr = x + 3 * (long)rv.x;
        a0 += nrm * xr[0];
        a1 += nrm * xr[1];
        a2 += nrm * xr[2];
        a3 += __int_as_float(rv.z);
        a4 += __int_as_float(rv.w);
    }
    float inv = 1.0f / fmaxf((float)dg, 1.0f);
    float m[5] = {a0 * inv, a1 * inv, a2 * inv, a3 * inv, a4 * inv};
    float xv[3];
#pragma unroll
    for (int j = 0; j < 3; j++) xv[j] = x[3 * (long)i + j];
    float o[16];
#pragma unroll
    for (int k = 0; k < 16; k++) {
        float v = sbc[k];
#pragma unroll
        for (int j = 0; j < 3; j++) v += xv[j] * sWc[j * 16 + k];
#pragma unroll
        for (int j = 0; j < 5; j++) v += m[j] * sWn[j * 16 + k];
        o[k] = fmaxf(v, 0.0f);
    }
    float4* hp = (float4*)(h + 16 * (long)i);
#pragma unroll
    for (int q = 0; q < 4; q++)
        hp[q] = make_float4(o[4 * q], o[4 * q + 1], o[4 * q + 2], o[4 * q + 3]);
}

// ------------------------------- gather L2 + node update + pooling (fused)
__global__ void k_gather2(const float* __restrict__ h, const int4* __restrict__ rec,
                          const int* __restrict__ base, const int* __restrict__ cnt,
                          const int* __restrict__ batch,
                          const float* __restrict__ Wc, const float* __restrict__ bc,
                          const float* __restrict__ Wn,
                          float* __restrict__ pool, int* __restrict__ poolcnt, int N) {
    __shared__ float sWc[16 * 16], sbc[16], sWn[18 * 16];
    __shared__ float sp[64 * 16];
    __shared__ int   sc[64];
    for (int t = threadIdx.x; t < 256; t += blockDim.x) sWc[t] = Wc[t];
    for (int t = threadIdx.x; t < 16;  t += blockDim.x) sbc[t] = bc[t];
    for (int t = threadIdx.x; t < 288; t += blockDim.x) sWn[t] = Wn[t];
    for (int t = threadIdx.x; t < 1024; t += blockDim.x) sp[t] = 0.0f;
    for (int t = threadIdx.x; t < 64;  t += blockDim.x) sc[t] = 0;
    __syncthreads();
    int i = blockIdx.x * blockDim.x + threadIdx.x;
    if (i < N) {
        int b0 = base[i], dg = cnt[i];
        float m[18];
#pragma unroll
        for (int j = 0; j < 18; j++) m[j] = 0.0f;
        for (int k = 0; k < dg; k++) {
            int4 rv = rec[b0 + k];
            float nrm = __int_as_float(rv.y);
            const float4* hr = (const float4*)(h + 16 * (long)rv.x);
            float4 h0 = hr[0], h1 = hr[1], h2 = hr[2], h3 = hr[3];
            m[0]  += nrm * h0.x;  m[1]  += nrm * h0.y;
            m[2]  += nrm * h0.z;  m[3]  += nrm * h0.w;
            m[4]  += nrm * h1.x;  m[5]  += nrm * h1.y;
            m[6]  += nrm * h1.z;  m[7]  += nrm * h1.w;
            m[8]  += nrm * h2.x;  m[9]  += nrm * h2.y;
            m[10] += nrm * h2.z;  m[11] += nrm * h2.w;
            m[12] += nrm * h3.x;  m[13] += nrm * h3.y;
            m[14] += nrm * h3.z;  m[15] += nrm * h3.w;
            m[16] += __int_as_float(rv.z);
            m[17] += __int_as_float(rv.w);
        }
        float inv = 1.0f / fmaxf((float)dg, 1.0f);
#pragma unroll
        for (int j = 0; j < 18; j++) m[j] *= inv;
        float hv[16];
        const float4* hp = (const float4*)(h + 16 * (long)i);
#pragma unroll
        for (int q = 0; q < 4; q++) {
            float4 t4 = hp[q];
            hv[4 * q] = t4.x; hv[4 * q + 1] = t4.y;
            hv[4 * q + 2] = t4.z; hv[4 * q + 3] = t4.w;
        }
        int b = batch[i];
        atomicAdd(&sc[b], 1);
#pragma unroll
        for (int k = 0; k < 16; k++) {
            float v = sbc[k];
#pragma unroll
            for (int j = 0; j < 16; j++) v += hv[j] * sWc[j * 16 + k];
#pragma unroll
            for (int j = 0; j < 18; j++) v += m[j] * sWn[j * 16 + k];
            v = fmaxf(v, 0.0f);
            unsafeAtomicAdd(&sp[b * 16 + k], v);
        }
    }
    __syncthreads();
    for (int t = threadIdx.x; t < 1024; t += blockDim.x)
        if (sp[t] != 0.0f) unsafeAtomicAdd(&pool[t], sp[t]);
    for (int t = threadIdx.x; t < 64; t += blockDim.x)
        if (sc[t]) atomicAdd(&poolcnt[t], sc[t]);
}

// ---------------------------------------------------------------- MLP head
__global__ void k_final(const float* __restrict__ pool, const int* __restrict__ poolcnt,
                        const float* __restrict__ Wl1, const float* __restrict__ bl1,
                        const float* __restrict__ Wl2, const float* __restrict__ bl2,
                        float* __restrict__ out) {
    int g = threadIdx.x;
    if (g >= 64) return;
    float inv = 1.0f / fmaxf((float)poolcnt[g], 1.0f);
    float gv[16];
#pragma unroll
    for (int k = 0; k < 16; k++) gv[k] = pool[g * 16 + k] * inv;
    float t[16];
#pragma unroll
    for (int k = 0; k < 16; k++) {
        float v = bl1[k];
#pragma unroll
        for (int j = 0; j < 16; j++) v += gv[j] * Wl1[j * 16 + k];
        t[k] = fmaxf(v, 0.0f);
    }
    float o0 = bl2[0], o1 = bl2[1];
#pragma unroll
    for (int j = 0; j < 16; j++) {
        o0 += t[j] * Wl2[j * 2 + 0];
        o1 += t[j] * Wl2[j * 2 + 1];
    }
    out[2 * g + 0] = o0;
    out[2 * g + 1] = o1;
}

extern "C" void kernel_launch(void* const* d_in, const int* in_sizes, int n_in,
                              void* d_out, int out_size, void* d_ws, size_t ws_size,
                              hipStream_t stream) {
    const float* x     = (const float*)d_in[0];
    const int*   ei    = (const int*)  d_in[1];
    const float* ea    = (const float*)d_in[2];
    const int*   batch = (const int*)  d_in[3];
    const float* Wc1   = (const float*)d_in[4];
    const float* bc1   = (const float*)d_in[5];
    const float* Wn1   = (const float*)d_in[6];
    const float* Wc2   = (const float*)d_in[7];
    const float* bc2   = (const float*)d_in[8];
    const float* Wn2   = (const float*)d_in[9];
    const float* Wl1   = (const float*)d_in[10];
    const float* bl1   = (const float*)d_in[11];
    const float* Wl2   = (const float*)d_in[12];
    const float* bl2   = (const float*)d_in[13];
    float* out = (float*)d_out;

    const int N  = in_sizes[0] / 3;
    const int E  = in_sizes[1] / 2;
    const int NN = (N + 1) & ~1;                  // u16 arrays padded to int
    const int NB = (N + 255) / 256;
    const int chunks = (N + CBINS - 1) >> CBITS;

    // workspace accounting; shrink P if tight
    auto wsNeeded = [&](int P) -> size_t {
        size_t s = 0;
        s += 4352 + 256;                                   // pool+poolcnt
        s += 3 * (((size_t)N * 4 + 255) & ~(size_t)255);   // dis,cnt,base
        s += ((size_t)NB * 4 + 255) & ~(size_t)255;        // bsum
        s += ((size_t)P * NN * 2 + 255) & ~(size_t)255;    // offC (u16)
        size_t trans = (size_t)P * NN * 2;                 // partialR (u16)
        size_t recb  = (size_t)E * 16;                     // rec
        s += ((trans > recb ? trans : recb) + 255) & ~(size_t)255;
        s += (size_t)N * 16 * 4;                           // h
        return s + 4096;
    };
    int P = 128;
    while (P > 16 && wsNeeded(P) > ws_size) P >>= 1;
    const int sliceLen = (E + P - 1) / P;

    char* ws = (char*)d_ws;
    size_t o = 0;
    auto alloc = [&](size_t bytes) {
        void* p = ws + o;
        o += (bytes + 255) & ~(size_t)255;
        return p;
    };
    // zeroed region (pool + poolcnt only)
    float* pool    = (float*)alloc(64 * 16 * 4);
    int*   poolcnt = (int*)  alloc(64 * 4);
    size_t zbytes = o;
    // non-zeroed (fully overwritten before read)
    float* dis  = (float*)alloc((size_t)N * 4);
    int*   cnt  = (int*)  alloc((size_t)N * 4);
    int*   base = (int*)  alloc((size_t)N * 4);
    int*   bsum = (int*)  alloc((size_t)NB * 4);
    unsigned short* offC = (unsigned short*)alloc((size_t)P * NN * 2);
    // overlay: partialR (dead after k_reduce) shares space with rec
    size_t ovStart = o;
    unsigned short* partialR = (unsigned short*)(ws + ovStart);
    size_t trans = (size_t)P * NN * 2, recb = (size_t)E * 16;
    int4*  rec = (int4*)(ws + ovStart);
    o = ovStart + (((trans > recb ? trans : recb) + 255) & ~(size_t)255);
    float* h = (float*)alloc((size_t)N * 16 * 4);
    (void)ws_size;

    hipMemsetAsync(d_ws, 0, zbytes, stream);

    int gN = (N + TPB - 1) / TPB;
    k_hist   <<<dim3(P, chunks, 2), TPB, 0, stream>>>(ei, E, N, sliceLen,
                                                      partialR, offC, NN);
    k_reduce <<<NB, 256, 0, stream>>>(partialR, offC, N, NN, P, dis, cnt, bsum);
    k_scan2  <<<1, 256, 0, stream>>>(bsum, NB);
    k_scan3  <<<NB, 256, 0, stream>>>(cnt, bsum, base, N);
    k_scatter<<<dim3(P, chunks), TPB, 0, stream>>>(ei, ea, dis, base, offC, rec,
                                                   E, N, NN, sliceLen);
    k_gather1<<<gN, TPB, 0, stream>>>(x, rec, base, cnt, Wc1, bc1, Wn1, h, N);
    k_gather2<<<gN, TPB, 0, stream>>>(h, rec, base, cnt, batch, Wc2, bc2, Wn2,
                                      pool, poolcnt, N);
    k_final  <<<1, 64, 0, stream>>>(pool, poolcnt, Wl1, bl1, Wl2, bl2, out);
}